// Round 1
// baseline (418.018 us; speedup 1.0000x reference)
//
#include <hip/hip_runtime.h>

#define HW 4096
#define CDIM 256

typedef _Float16 half8 __attribute__((ext_vector_type(8)));
typedef float f32x4 __attribute__((ext_vector_type(4)));

__device__ __forceinline__ void top3_ins(float v, float& a0, float& a1, float& a2) {
  // insert v into descending (a0 >= a1 >= a2)
  float m01 = fminf(a0, v);
  a0 = fmaxf(a0, v);
  float m12 = fminf(a1, m01);
  a1 = fmaxf(a1, m01);
  a2 = fmaxf(a2, m12);
}

__device__ __forceinline__ float mask_val(const float* gtab, int s, int t) {
  int dr = (s >> 6) - (t >> 6); dr = dr < 0 ? -dr : dr;
  int dc = (s & 63) - (t & 63); dc = dc < 0 ? -dc : dc;
  return 1.0f - gtab[dr] * gtab[dc];
}

// E-tile GEMM core: D[m][n] = dot(Xf[row mBase+m], Xf[row nBase+n]) over k=0..255.
// A/B frag layout (16x16x32 f16): idx = lane&15 (row of the operand matrix),
// k = (lane>>4)*8 + j.  C/D: col = lane&15, row = (lane>>4)*4 + reg.
__device__ __forceinline__ void wave_gemm(const _Float16* __restrict__ X,
                                          int mBase, int nBase, int lane,
                                          f32x4 acc[4][4]) {
#pragma unroll
  for (int mi = 0; mi < 4; ++mi)
#pragma unroll
    for (int ni = 0; ni < 4; ++ni) acc[mi][ni] = (f32x4){0.f, 0.f, 0.f, 0.f};
  const _Float16* aptr = X + (size_t)(mBase + (lane & 15)) * CDIM + ((lane >> 4) << 3);
  const _Float16* bptr = X + (size_t)(nBase + (lane & 15)) * CDIM + ((lane >> 4) << 3);
#pragma unroll 2
  for (int k0 = 0; k0 < CDIM; k0 += 32) {
    half8 a[4], b[4];
#pragma unroll
    for (int i = 0; i < 4; ++i) a[i] = *(const half8*)(aptr + (size_t)(16 * i) * CDIM + k0);
#pragma unroll
    for (int i = 0; i < 4; ++i) b[i] = *(const half8*)(bptr + (size_t)(16 * i) * CDIM + k0);
#pragma unroll
    for (int mi = 0; mi < 4; ++mi)
#pragma unroll
      for (int ni = 0; ni < 4; ++ni)
        acc[mi][ni] = __builtin_amdgcn_mfma_f32_16x16x32_f16(a[mi], b[ni], acc[mi][ni], 0, 0, 0);
  }
}

// ---------------- kernel 1: channel-L2 normalize + fp16 transpose ----------------
// x: (b, c, hw) fp32  ->  Xf: (b, hw, c) fp16
__global__ void __launch_bounds__(256) normalize_k(const float* __restrict__ x,
                                                   _Float16* __restrict__ Xf) {
  const int idx = blockIdx.x * 256 + threadIdx.x;  // b*HW + p, 8192 total
  const int b = idx >> 12;
  const int p = idx & (HW - 1);
  const float* xb = x + (size_t)b * CDIM * HW + p;
  float ss = 0.f;
  for (int c = 0; c < CDIM; ++c) {
    float v = xb[(size_t)c * HW];
    ss += v * v;
  }
  const float scale = 1.0f / fmaxf(sqrtf(ss), 1e-12f);
  _Float16* o = Xf + (size_t)idx * CDIM;
  for (int c = 0; c < CDIM; c += 8) {
    half8 h;
#pragma unroll
    for (int j = 0; j < 8; ++j) h[j] = (_Float16)(xb[(size_t)(c + j) * HW] * scale);
    *(half8*)(o + c) = h;
  }
}

// ---------------- pass A: row sums R[s] = sum_t exp(alpha*mask*aff) ----------------
__global__ void __launch_bounds__(256) passA_k(const _Float16* __restrict__ Xf,
                                               const float* __restrict__ alphap,
                                               float* __restrict__ R) {
  __shared__ float gtab[64];
  if (threadIdx.x < 64) {
    float d = (float)threadIdx.x;
    gtab[threadIdx.x] = __expf(-d * d * 0.048828125f);
  }
  __syncthreads();
  const float alpha = alphap[0];
  const int b = blockIdx.z;
  const _Float16* X = Xf + (size_t)b * HW * CDIM;
  const int lane = threadIdx.x & 63;
  const int w = threadIdx.x >> 6;
  const int mBase = blockIdx.y * 128 + (w >> 1) * 64;  // s rows
  const int nBase = blockIdx.x * 128 + (w & 1) * 64;   // t cols
  f32x4 acc[4][4];
  wave_gemm(X, mBase, nBase, lane, acc);
  const int quad = lane >> 4;
  float rsum[4][4];
#pragma unroll
  for (int mi = 0; mi < 4; ++mi)
#pragma unroll
    for (int r = 0; r < 4; ++r) rsum[mi][r] = 0.f;
#pragma unroll
  for (int mi = 0; mi < 4; ++mi) {
#pragma unroll
    for (int r = 0; r < 4; ++r) {
      const int s = mBase + mi * 16 + quad * 4 + r;
#pragma unroll
      for (int ni = 0; ni < 4; ++ni) {
        const int t = nBase + ni * 16 + (lane & 15);
        float e = __expf(alpha * mask_val(gtab, s, t) * acc[mi][ni][r]);
        rsum[mi][r] += e;
      }
    }
  }
#pragma unroll
  for (int off = 1; off < 16; off <<= 1) {
#pragma unroll
    for (int mi = 0; mi < 4; ++mi)
#pragma unroll
      for (int r = 0; r < 4; ++r) rsum[mi][r] += __shfl_xor(rsum[mi][r], off);
  }
  if ((lane & 15) == 0) {
#pragma unroll
    for (int mi = 0; mi < 4; ++mi)
#pragma unroll
      for (int r = 0; r < 4; ++r)
        atomicAdd(&R[b * HW + mBase + mi * 16 + quad * 4 + r], rsum[mi][r]);
  }
}

// ---- pass B: T[t] = sum_s E^2/R[s]  + per-64-col partial top-3 of g=E^2/R[s] ----
// Tile rows = t, cols = s (valid because E is symmetric).
__global__ void __launch_bounds__(256) passB_k(const _Float16* __restrict__ Xf,
                                               const float* __restrict__ alphap,
                                               const float* __restrict__ R,
                                               float* __restrict__ T,
                                               float* __restrict__ part) {
  __shared__ float gtab[64];
  if (threadIdx.x < 64) {
    float d = (float)threadIdx.x;
    gtab[threadIdx.x] = __expf(-d * d * 0.048828125f);
  }
  __syncthreads();
  const float alpha = alphap[0];
  const int b = blockIdx.z;
  const _Float16* X = Xf + (size_t)b * HW * CDIM;
  const int lane = threadIdx.x & 63;
  const int w = threadIdx.x >> 6;
  const int mBase = blockIdx.y * 128 + (w >> 1) * 64;  // t rows
  const int nBase = blockIdx.x * 128 + (w & 1) * 64;   // s cols
  f32x4 acc[4][4];
  wave_gemm(X, mBase, nBase, lane, acc);
  const int quad = lane >> 4;
  float invRs[4];
#pragma unroll
  for (int ni = 0; ni < 4; ++ni)
    invRs[ni] = 1.0f / R[b * HW + nBase + ni * 16 + (lane & 15)];
  float tsum[4][4], b0[4][4], b1[4][4], b2[4][4];
#pragma unroll
  for (int mi = 0; mi < 4; ++mi)
#pragma unroll
    for (int r = 0; r < 4; ++r) {
      tsum[mi][r] = 0.f; b0[mi][r] = 0.f; b1[mi][r] = 0.f; b2[mi][r] = 0.f;
    }
#pragma unroll
  for (int mi = 0; mi < 4; ++mi) {
#pragma unroll
    for (int r = 0; r < 4; ++r) {
      const int tt = mBase + mi * 16 + quad * 4 + r;
#pragma unroll
      for (int ni = 0; ni < 4; ++ni) {
        const int ss = nBase + ni * 16 + (lane & 15);
        float e = __expf(alpha * mask_val(gtab, tt, ss) * acc[mi][ni][r]);
        float gv = e * e * invRs[ni];
        tsum[mi][r] += gv;
        top3_ins(gv, b0[mi][r], b1[mi][r], b2[mi][r]);
      }
    }
  }
#pragma unroll
  for (int off = 1; off < 16; off <<= 1) {
#pragma unroll
    for (int mi = 0; mi < 4; ++mi)
#pragma unroll
      for (int r = 0; r < 4; ++r) {
        tsum[mi][r] += __shfl_xor(tsum[mi][r], off);
        float o0 = __shfl_xor(b0[mi][r], off);
        float o1 = __shfl_xor(b1[mi][r], off);
        float o2 = __shfl_xor(b2[mi][r], off);
        top3_ins(o0, b0[mi][r], b1[mi][r], b2[mi][r]);
        top3_ins(o1, b0[mi][r], b1[mi][r], b2[mi][r]);
        top3_ins(o2, b0[mi][r], b1[mi][r], b2[mi][r]);
      }
  }
  if ((lane & 15) == 0) {
    const int blkI = blockIdx.x * 2 + (w & 1);  // 0..63 s-block id
#pragma unroll
    for (int mi = 0; mi < 4; ++mi)
#pragma unroll
      for (int r = 0; r < 4; ++r) {
        const int tt = mBase + mi * 16 + quad * 4 + r;
        atomicAdd(&T[b * HW + tt], tsum[mi][r]);
        float* pp = part + ((size_t)(b * 64 + blkI) * HW + tt) * 3;
        pp[0] = b0[mi][r];
        pp[1] = b1[mi][r];
        pp[2] = b2[mi][r];
      }
  }
}

// ---------------- merge: final top3 -> val; W[t] = 1/(T + 1e-8*R); invR ----------------
__global__ void __launch_bounds__(256) merge_k(const float* __restrict__ R,
                                               const float* __restrict__ T,
                                               const float* __restrict__ part,
                                               float* __restrict__ W,
                                               float* __restrict__ invRa,
                                               float* __restrict__ val_out) {
  const int idx = blockIdx.x * 256 + threadIdx.x;  // b*HW + t, 8192 total
  const int b = idx >> 12;
  const int t = idx & (HW - 1);
  float a0 = 0.f, a1 = 0.f, a2 = 0.f;
  const float* p = part + (size_t)(b * 64) * HW * 3 + (size_t)t * 3;
  for (int blkI = 0; blkI < 64; ++blkI) {
    const float* pp = p + (size_t)blkI * HW * 3;
    top3_ins(pp[0], a0, a1, a2);
    top3_ins(pp[1], a0, a1, a2);
    top3_ins(pp[2], a0, a1, a2);
  }
  const float r = R[idx];
  const float invr = 1.0f / r;
  // val = top3 of x_c over s = top3(g)/C_t, with C_t = R_t by symmetry
  val_out[(b * 3 + 0) * HW + t] = a0 * invr;
  val_out[(b * 3 + 1) * HW + t] = a1 * invr;
  val_out[(b * 3 + 2) * HW + t] = a2 * invr;
  invRa[idx] = invr;
  W[idx] = 1.0f / (T[idx] + 1e-8f * r);
}

// ---------------- pass C: x_soft[s,t] = E^2 * invR[s] * W[t] ----------------
__global__ void __launch_bounds__(256) passC_k(const _Float16* __restrict__ Xf,
                                               const float* __restrict__ alphap,
                                               const float* __restrict__ invRa,
                                               const float* __restrict__ W,
                                               float* __restrict__ xsoft) {
  __shared__ float gtab[64];
  if (threadIdx.x < 64) {
    float d = (float)threadIdx.x;
    gtab[threadIdx.x] = __expf(-d * d * 0.048828125f);
  }
  __syncthreads();
  const float alpha = alphap[0];
  const int b = blockIdx.z;
  const _Float16* X = Xf + (size_t)b * HW * CDIM;
  const int lane = threadIdx.x & 63;
  const int w = threadIdx.x >> 6;
  const int mBase = blockIdx.y * 128 + (w >> 1) * 64;  // s rows
  const int nBase = blockIdx.x * 128 + (w & 1) * 64;   // t cols
  f32x4 acc[4][4];
  wave_gemm(X, mBase, nBase, lane, acc);
  const int quad = lane >> 4;
  float wc[4];
#pragma unroll
  for (int ni = 0; ni < 4; ++ni) wc[ni] = W[b * HW + nBase + ni * 16 + (lane & 15)];
  float ir[4][4];
#pragma unroll
  for (int mi = 0; mi < 4; ++mi)
#pragma unroll
    for (int r = 0; r < 4; ++r)
      ir[mi][r] = invRa[b * HW + mBase + mi * 16 + quad * 4 + r];
#pragma unroll
  for (int mi = 0; mi < 4; ++mi) {
#pragma unroll
    for (int r = 0; r < 4; ++r) {
      const int s = mBase + mi * 16 + quad * 4 + r;
      float* orow = xsoft + (size_t)(b * HW + s) * HW;
#pragma unroll
      for (int ni = 0; ni < 4; ++ni) {
        const int t = nBase + ni * 16 + (lane & 15);
        float e = __expf(alpha * mask_val(gtab, s, t) * acc[mi][ni][r]);
        orow[t] = e * e * ir[mi][r] * wc[ni];
      }
    }
  }
}

extern "C" void kernel_launch(void* const* d_in, const int* in_sizes, int n_in,
                              void* d_out, int out_size, void* d_ws, size_t ws_size,
                              hipStream_t stream) {
  const float* x = (const float*)d_in[0];
  const float* alphap = (const float*)d_in[1];
  float* out = (float*)d_out;
  char* ws = (char*)d_ws;

  // workspace layout
  _Float16* Xf = (_Float16*)ws;                      // 2*4096*256*2 = 4 MB
  float* R = (float*)(ws + (size_t)4194304);         // 32 KB
  float* T = R + 2 * HW;                             // 32 KB
  float* W = T + 2 * HW;                             // 32 KB
  float* invRa = W + 2 * HW;                         // 32 KB
  float* part = invRa + 2 * HW;                      // 2*64*4096*3*4 = 6 MB

  hipMemsetAsync(R, 0, (size_t)2 * HW * 2 * sizeof(float), stream);  // zero R and T

  normalize_k<<<dim3(32), dim3(256), 0, stream>>>(x, Xf);
  dim3 g(32, 32, 2), blk(256);
  passA_k<<<g, blk, 0, stream>>>(Xf, alphap, R);
  passB_k<<<g, blk, 0, stream>>>(Xf, alphap, R, T, part);
  merge_k<<<dim3(32), dim3(256), 0, stream>>>(R, T, part, W, invRa, out);
  passC_k<<<g, blk, 0, stream>>>(Xf, alphap, invRa, W, out + 2 * 3 * HW);
}

// Round 2
// 324.563 us; speedup vs baseline: 1.2879x; 1.2879x over previous
//
#include <hip/hip_runtime.h>

#define HW 4096
#define CDIM 256
#define BK 32

typedef _Float16 half8 __attribute__((ext_vector_type(8)));
typedef float f32x4 __attribute__((ext_vector_type(4)));

__device__ __forceinline__ void top3_ins(float v, float& a0, float& a1, float& a2) {
  float m01 = fminf(a0, v);
  a0 = fmaxf(a0, v);
  float m12 = fminf(a1, m01);
  a1 = fmaxf(a1, m01);
  a2 = fmaxf(a2, m12);
}

__device__ __forceinline__ float mask_val(const float* gtab, int s, int t) {
  int dr = (s >> 6) - (t >> 6); dr = dr < 0 ? -dr : dr;
  int dc = (s & 63) - (t & 63); dc = dc < 0 ? -dc : dc;
  return 1.0f - gtab[dr] * gtab[dc];
}

__device__ __forceinline__ void async_copy16(const void* g, void* l) {
  __builtin_amdgcn_global_load_lds((const __attribute__((address_space(1))) void*)g,
                                   (__attribute__((address_space(3))) void*)l, 16, 0, 0);
}

// Stage one 128x32 fp16 k-slice into LDS (row-major, 64B rows, no pad — required
// by global_load_lds lane-contiguity). Wave w stages rows [w*32, w*32+32).
__device__ __forceinline__ void stage_slice(const _Float16* __restrict__ X,
                                            int rowBase, int k0,
                                            _Float16* sdst, int w, int lane) {
#pragma unroll
  for (int i = 0; i < 2; ++i) {
    const int rchunk = w * 32 + i * 16;
    const _Float16* g = X + (size_t)(rowBase + rchunk + (lane >> 2)) * CDIM + k0 + ((lane & 3) << 3);
    async_copy16(g, sdst + rchunk * BK);  // HW adds lane*16B
  }
}

// 128x128 workgroup tile Gram GEMM: acc[m][n] = dot(X[mBase+..], X[nBase+..]) over 256 ch.
// Wave w at (wr=w>>1, wc=w&1) owns the 64x64 subtile; 4x4 frags of 16x16.
// A/B frag layout (16x16x32 f16): idx=lane&15, k=(lane>>4)*8+j. C/D: col=lane&15, row=(lane>>4)*4+reg.
__device__ __forceinline__ void tile_gemm(const _Float16* __restrict__ X,
                                          int mBase, int nBase,
                                          int w, int lane, f32x4 acc[4][4]) {
  __shared__ _Float16 sA[2][128 * BK];
  __shared__ _Float16 sB[2][128 * BK];
#pragma unroll
  for (int mi = 0; mi < 4; ++mi)
#pragma unroll
    for (int ni = 0; ni < 4; ++ni) acc[mi][ni] = (f32x4){0.f, 0.f, 0.f, 0.f};

  const int wr = w >> 1, wc = w & 1;
  const int aRow0 = wr * 64 + (lane & 15);
  const int bRow0 = wc * 64 + (lane & 15);
  const int kOff = (lane >> 4) << 3;

  stage_slice(X, mBase, 0, sA[0], w, lane);
  stage_slice(X, nBase, 0, sB[0], w, lane);

  int cur = 0;
#pragma unroll
  for (int k0 = 0; k0 < CDIM; k0 += BK) {
    __syncthreads();  // drains vmcnt (staging of buf[cur] done) + lgkmcnt (prev reads done)
    if (k0 + BK < CDIM) {
      stage_slice(X, mBase, k0 + BK, sA[cur ^ 1], w, lane);
      stage_slice(X, nBase, k0 + BK, sB[cur ^ 1], w, lane);
    }
    half8 a[4], b[4];
#pragma unroll
    for (int i = 0; i < 4; ++i)
      a[i] = *(const half8*)(sA[cur] + (aRow0 + 16 * i) * BK + kOff);
#pragma unroll
    for (int i = 0; i < 4; ++i)
      b[i] = *(const half8*)(sB[cur] + (bRow0 + 16 * i) * BK + kOff);
#pragma unroll
    for (int mi = 0; mi < 4; ++mi)
#pragma unroll
      for (int ni = 0; ni < 4; ++ni)
        acc[mi][ni] = __builtin_amdgcn_mfma_f32_16x16x32_f16(a[mi], b[ni], acc[mi][ni], 0, 0, 0);
    // second half of the k-slice (BK=32 -> one mfma k=32 covers it; BK==32 == mfma K, done)
    cur ^= 1;
  }
}

// ---------------- kernel 1: channel-L2 normalize + fp16 transpose ----------------
__global__ void __launch_bounds__(256) normalize_k(const float* __restrict__ x,
                                                   _Float16* __restrict__ Xf) {
  const int idx = blockIdx.x * 256 + threadIdx.x;  // b*HW + p
  const int b = idx >> 12;
  const int p = idx & (HW - 1);
  const float* xb = x + (size_t)b * CDIM * HW + p;
  float ss = 0.f;
  for (int c = 0; c < CDIM; ++c) {
    float v = xb[(size_t)c * HW];
    ss += v * v;
  }
  const float scale = 1.0f / fmaxf(sqrtf(ss), 1e-12f);
  _Float16* o = Xf + (size_t)idx * CDIM;
  for (int c = 0; c < CDIM; c += 8) {
    half8 h;
#pragma unroll
    for (int j = 0; j < 8; ++j) h[j] = (_Float16)(xb[(size_t)(c + j) * HW] * scale);
    *(half8*)(o + c) = h;
  }
}

// ---------------- pass A: R[s] = sum_t exp(alpha*mask*aff) ----------------
__global__ void __launch_bounds__(256) passA_k(const _Float16* __restrict__ Xf,
                                               const float* __restrict__ alphap,
                                               float* __restrict__ R) {
  __shared__ float gtab[64];
  if (threadIdx.x < 64) {
    float d = (float)threadIdx.x;
    gtab[threadIdx.x] = __expf(-d * d * 0.048828125f);
  }
  __syncthreads();
  const float alpha = alphap[0];
  const int b = blockIdx.z;
  const _Float16* X = Xf + (size_t)b * HW * CDIM;
  const int lane = threadIdx.x & 63;
  const int w = threadIdx.x >> 6;
  const int mBase = blockIdx.y * 128;
  const int nBase = blockIdx.x * 128;
  f32x4 acc[4][4];
  tile_gemm(X, mBase, nBase, w, lane, acc);
  const int wr = w >> 1, wc = w & 1;
  const int quad = lane >> 4;
  float rsum[4][4];
#pragma unroll
  for (int mi = 0; mi < 4; ++mi)
#pragma unroll
    for (int r = 0; r < 4; ++r) rsum[mi][r] = 0.f;
#pragma unroll
  for (int mi = 0; mi < 4; ++mi) {
#pragma unroll
    for (int r = 0; r < 4; ++r) {
      const int s = mBase + wr * 64 + mi * 16 + quad * 4 + r;
#pragma unroll
      for (int ni = 0; ni < 4; ++ni) {
        const int t = nBase + wc * 64 + ni * 16 + (lane & 15);
        rsum[mi][r] += __expf(alpha * mask_val(gtab, s, t) * acc[mi][ni][r]);
      }
    }
  }
#pragma unroll
  for (int off = 1; off < 16; off <<= 1)
#pragma unroll
    for (int mi = 0; mi < 4; ++mi)
#pragma unroll
      for (int r = 0; r < 4; ++r) rsum[mi][r] += __shfl_xor(rsum[mi][r], off);
  if ((lane & 15) == 0) {
#pragma unroll
    for (int mi = 0; mi < 4; ++mi)
#pragma unroll
      for (int r = 0; r < 4; ++r)
        atomicAdd(&R[b * HW + mBase + wr * 64 + mi * 16 + quad * 4 + r], rsum[mi][r]);
  }
}

// ---- pass B: T[t] = sum_s E^2/R[s] + per-64-col partial top-3 (rows=t, cols=s; E symmetric) ----
__global__ void __launch_bounds__(256) passB_k(const _Float16* __restrict__ Xf,
                                               const float* __restrict__ alphap,
                                               const float* __restrict__ R,
                                               float* __restrict__ T,
                                               float* __restrict__ part) {
  __shared__ float gtab[64];
  if (threadIdx.x < 64) {
    float d = (float)threadIdx.x;
    gtab[threadIdx.x] = __expf(-d * d * 0.048828125f);
  }
  __syncthreads();
  const float alpha = alphap[0];
  const int b = blockIdx.z;
  const _Float16* X = Xf + (size_t)b * HW * CDIM;
  const int lane = threadIdx.x & 63;
  const int w = threadIdx.x >> 6;
  const int mBase = blockIdx.y * 128;  // t
  const int nBase = blockIdx.x * 128;  // s
  f32x4 acc[4][4];
  tile_gemm(X, mBase, nBase, w, lane, acc);
  const int wr = w >> 1, wc = w & 1;
  const int quad = lane >> 4;
  float invRs[4];
#pragma unroll
  for (int ni = 0; ni < 4; ++ni)
    invRs[ni] = 1.0f / R[b * HW + nBase + wc * 64 + ni * 16 + (lane & 15)];
  float tsum[4][4], b0[4][4], b1[4][4], b2[4][4];
#pragma unroll
  for (int mi = 0; mi < 4; ++mi)
#pragma unroll
    for (int r = 0; r < 4; ++r) {
      tsum[mi][r] = 0.f; b0[mi][r] = 0.f; b1[mi][r] = 0.f; b2[mi][r] = 0.f;
    }
#pragma unroll
  for (int mi = 0; mi < 4; ++mi) {
#pragma unroll
    for (int r = 0; r < 4; ++r) {
      const int tt = mBase + wr * 64 + mi * 16 + quad * 4 + r;
#pragma unroll
      for (int ni = 0; ni < 4; ++ni) {
        const int ss = nBase + wc * 64 + ni * 16 + (lane & 15);
        float e = __expf(alpha * mask_val(gtab, tt, ss) * acc[mi][ni][r]);
        float gv = e * e * invRs[ni];
        tsum[mi][r] += gv;
        top3_ins(gv, b0[mi][r], b1[mi][r], b2[mi][r]);
      }
    }
  }
#pragma unroll
  for (int off = 1; off < 16; off <<= 1)
#pragma unroll
    for (int mi = 0; mi < 4; ++mi)
#pragma unroll
      for (int r = 0; r < 4; ++r) {
        tsum[mi][r] += __shfl_xor(tsum[mi][r], off);
        float o0 = __shfl_xor(b0[mi][r], off);
        float o1 = __shfl_xor(b1[mi][r], off);
        float o2 = __shfl_xor(b2[mi][r], off);
        top3_ins(o0, b0[mi][r], b1[mi][r], b2[mi][r]);
        top3_ins(o1, b0[mi][r], b1[mi][r], b2[mi][r]);
        top3_ins(o2, b0[mi][r], b1[mi][r], b2[mi][r]);
      }
  if ((lane & 15) == 0) {
    const int blkI = blockIdx.x * 2 + wc;  // 0..63 s-block id
#pragma unroll
    for (int mi = 0; mi < 4; ++mi)
#pragma unroll
      for (int r = 0; r < 4; ++r) {
        const int tt = mBase + wr * 64 + mi * 16 + quad * 4 + r;
        atomicAdd(&T[b * HW + tt], tsum[mi][r]);
        float* pp = part + ((size_t)(b * 64 + blkI) * HW + tt) * 3;
        pp[0] = b0[mi][r];
        pp[1] = b1[mi][r];
        pp[2] = b2[mi][r];
      }
  }
}

// ---------------- merge: final top3 -> val; W[t] = 1/(T + 1e-8*R); invR ----------------
__global__ void __launch_bounds__(256) merge_k(const float* __restrict__ R,
                                               const float* __restrict__ T,
                                               const float* __restrict__ part,
                                               float* __restrict__ W,
                                               float* __restrict__ invRa,
                                               float* __restrict__ val_out) {
  const int idx = blockIdx.x * 256 + threadIdx.x;
  const int b = idx >> 12;
  const int t = idx & (HW - 1);
  float a0 = 0.f, a1 = 0.f, a2 = 0.f;
  const float* p = part + (size_t)(b * 64) * HW * 3 + (size_t)t * 3;
  for (int blkI = 0; blkI < 64; ++blkI) {
    const float* pp = p + (size_t)blkI * HW * 3;
    top3_ins(pp[0], a0, a1, a2);
    top3_ins(pp[1], a0, a1, a2);
    top3_ins(pp[2], a0, a1, a2);
  }
  const float r = R[idx];
  const float invr = 1.0f / r;
  val_out[(b * 3 + 0) * HW + t] = a0 * invr;  // col-sum C_t == R_t by symmetry
  val_out[(b * 3 + 1) * HW + t] = a1 * invr;
  val_out[(b * 3 + 2) * HW + t] = a2 * invr;
  invRa[idx] = invr;
  W[idx] = 1.0f / (T[idx] + 1e-8f * r);
}

// ---------------- pass C: x_soft[s,t] = E^2 * invR[s] * W[t] ----------------
__global__ void __launch_bounds__(256) passC_k(const _Float16* __restrict__ Xf,
                                               const float* __restrict__ alphap,
                                               const float* __restrict__ invRa,
                                               const float* __restrict__ W,
                                               float* __restrict__ xsoft) {
  __shared__ float gtab[64];
  if (threadIdx.x < 64) {
    float d = (float)threadIdx.x;
    gtab[threadIdx.x] = __expf(-d * d * 0.048828125f);
  }
  __syncthreads();
  const float alpha = alphap[0];
  const int b = blockIdx.z;
  const _Float16* X = Xf + (size_t)b * HW * CDIM;
  const int lane = threadIdx.x & 63;
  const int w = threadIdx.x >> 6;
  const int mBase = blockIdx.y * 128;  // s
  const int nBase = blockIdx.x * 128;  // t
  f32x4 acc[4][4];
  tile_gemm(X, mBase, nBase, w, lane, acc);
  const int wr = w >> 1, wc = w & 1;
  const int quad = lane >> 4;
  float wcoef[4];
#pragma unroll
  for (int ni = 0; ni < 4; ++ni)
    wcoef[ni] = W[b * HW + nBase + wc * 64 + ni * 16 + (lane & 15)];
  float ir[4][4];
#pragma unroll
  for (int mi = 0; mi < 4; ++mi)
#pragma unroll
    for (int r = 0; r < 4; ++r)
      ir[mi][r] = invRa[b * HW + mBase + wr * 64 + mi * 16 + quad * 4 + r];
#pragma unroll
  for (int mi = 0; mi < 4; ++mi) {
#pragma unroll
    for (int r = 0; r < 4; ++r) {
      const int s = mBase + wr * 64 + mi * 16 + quad * 4 + r;
      float* orow = xsoft + (size_t)(b * HW + s) * HW;
#pragma unroll
      for (int ni = 0; ni < 4; ++ni) {
        const int t = nBase + wc * 64 + ni * 16 + (lane & 15);
        float e = __expf(alpha * mask_val(gtab, s, t) * acc[mi][ni][r]);
        orow[t] = e * e * ir[mi][r] * wcoef[ni];
      }
    }
  }
}

extern "C" void kernel_launch(void* const* d_in, const int* in_sizes, int n_in,
                              void* d_out, int out_size, void* d_ws, size_t ws_size,
                              hipStream_t stream) {
  const float* x = (const float*)d_in[0];
  const float* alphap = (const float*)d_in[1];
  float* out = (float*)d_out;
  char* ws = (char*)d_ws;

  _Float16* Xf = (_Float16*)ws;                      // 4 MB
  float* R = (float*)(ws + (size_t)4194304);         // 32 KB
  float* T = R + 2 * HW;                             // 32 KB
  float* W = T + 2 * HW;                             // 32 KB
  float* invRa = W + 2 * HW;                         // 32 KB
  float* part = invRa + 2 * HW;                      // 6 MB

  hipMemsetAsync(R, 0, (size_t)2 * HW * 2 * sizeof(float), stream);  // zero R and T

  normalize_k<<<dim3(32), dim3(256), 0, stream>>>(x, Xf);
  dim3 g(32, 32, 2), blk(256);
  passA_k<<<g, blk, 0, stream>>>(Xf, alphap, R);
  passB_k<<<g, blk, 0, stream>>>(Xf, alphap, R, T, part);
  merge_k<<<dim3(32), dim3(256), 0, stream>>>(R, T, part, W, invRa, out);
  passC_k<<<g, blk, 0, stream>>>(Xf, alphap, invRa, W, out + 2 * 3 * HW);
}

// Round 3
// 223.166 us; speedup vs baseline: 1.8731x; 1.4544x over previous
//
#include <hip/hip_runtime.h>

#define HW 4096
#define CDIM 256
#define BK 32

typedef _Float16 half8 __attribute__((ext_vector_type(8)));
typedef float f32x4 __attribute__((ext_vector_type(4)));

__device__ __forceinline__ void top3_ins(float v, float& a0, float& a1, float& a2) {
  float m01 = fminf(a0, v);
  a0 = fmaxf(a0, v);
  float m12 = fminf(a1, m01);
  a1 = fmaxf(a1, m01);
  a2 = fmaxf(a2, m12);
}

__device__ __forceinline__ float mask_val(const float* gtab, int s, int t) {
  int dr = (s >> 6) - (t >> 6); dr = dr < 0 ? -dr : dr;
  int dc = (s & 63) - (t & 63); dc = dc < 0 ? -dc : dc;
  return 1.0f - gtab[dr] * gtab[dc];
}

__device__ __forceinline__ void async_copy16(const void* g, void* l) {
  __builtin_amdgcn_global_load_lds((const __attribute__((address_space(1))) void*)g,
                                   (__attribute__((address_space(3))) void*)l, 16, 0, 0);
}

// Swizzled LDS staging: slot(lane) = (row=lane>>2, chunk'=lane&3) within a 16-row
// group; it receives GLOBAL chunk c = (chunk' - (row>>1)) & 3 so that readers at
// chunk' = (q + (row>>1)) & 3 see global chunk q. Spreads 16-row b128 reads over
// all 8 bank-quads (2-way = free) instead of 8-way conflicts with raw 64B rows.
__device__ __forceinline__ void stage_slice(const _Float16* __restrict__ X,
                                            int rowBase, int k0,
                                            _Float16* sdst, int w, int lane) {
  const int csrc = ((lane & 3) - ((lane >> 3) & 3)) & 3;
#pragma unroll
  for (int i = 0; i < 2; ++i) {
    const int rchunk = w * 32 + i * 16;
    const _Float16* g =
        X + (size_t)(rowBase + rchunk + (lane >> 2)) * CDIM + k0 + csrc * 8;
    async_copy16(g, sdst + rchunk * BK);  // HW appends lane*16B
  }
}

// ---------------- kernel 1: channel-L2 normalize + fp16 transpose ----------------
// 256 blocks; block = 32 pixels x 8 channel-groups; values kept in 32 VGPRs.
__global__ void __launch_bounds__(256) normalize_k(const float* __restrict__ x,
                                                   _Float16* __restrict__ Xf) {
  const int p = threadIdx.x & 31;
  const int g = threadIdx.x >> 5;
  const int P0 = blockIdx.x * 32;           // flat pixel base (b*HW + p)
  const int b = P0 >> 12;
  const int ph = (P0 & (HW - 1)) + p;
  const float* xb = x + (size_t)b * CDIM * HW + ph;
  float vals[32];
  float ss = 0.f;
#pragma unroll
  for (int k = 0; k < 32; ++k) {
    float v = xb[(size_t)(g * 32 + k) * HW];
    vals[k] = v;
    ss += v * v;
  }
  __shared__ float ssqp[8][33];
  __shared__ float scl[32];
  ssqp[g][p] = ss;
  __syncthreads();
  if (threadIdx.x < 32) {
    float s2 = 0.f;
#pragma unroll
    for (int gg = 0; gg < 8; ++gg) s2 += ssqp[gg][threadIdx.x];
    scl[threadIdx.x] = 1.0f / fmaxf(sqrtf(s2), 1e-12f);
  }
  __syncthreads();
  const float sc = scl[p];
  _Float16* o = Xf + (size_t)(P0 + p) * CDIM + g * 32;
#pragma unroll
  for (int c8 = 0; c8 < 4; ++c8) {
    half8 h;
#pragma unroll
    for (int j = 0; j < 8; ++j) h[j] = (_Float16)(vals[c8 * 8 + j] * sc);
    *(half8*)(o + c8 * 8) = h;
  }
}

// ------------- kernel 2: one GEMM pass -> Q = E^2 (into out x_soft slot) + R -------------
// 128x128 tile, 4 waves of 64x64, double-buffered swizzled LDS staging.
// R[t] = col sums of E (== row sums by symmetry): cheap 2-level quad butterfly.
__global__ void __launch_bounds__(256, 3) gemmE_k(const _Float16* __restrict__ Xf,
                                                  const float* __restrict__ alphap,
                                                  float* __restrict__ R,
                                                  float* __restrict__ Q) {
  __shared__ _Float16 sA[2][128 * BK];
  __shared__ _Float16 sB[2][128 * BK];
  __shared__ float gtab[64];
  if (threadIdx.x < 64) {
    float d = (float)threadIdx.x;
    gtab[threadIdx.x] = __expf(-d * d * 0.048828125f);
  }
  const float alpha = alphap[0];
  const int b = blockIdx.z;
  const _Float16* X = Xf + (size_t)b * HW * CDIM;
  const int lane = threadIdx.x & 63;
  const int w = threadIdx.x >> 6;
  const int wr = w >> 1, wc = w & 1;
  const int mBase = blockIdx.y * 128;  // s
  const int nBase = blockIdx.x * 128;  // t

  f32x4 acc[4][4];
#pragma unroll
  for (int mi = 0; mi < 4; ++mi)
#pragma unroll
    for (int ni = 0; ni < 4; ++ni) acc[mi][ni] = (f32x4){0.f, 0.f, 0.f, 0.f};

  const int aRow0 = wr * 64 + (lane & 15);
  const int bRow0 = wc * 64 + (lane & 15);
  // swizzled chunk for this lane's quad (same for all 16-row steps)
  const int cswz = (((lane >> 4) + ((lane >> 1) & 3)) & 3) * 8;

  stage_slice(X, mBase, 0, sA[0], w, lane);
  stage_slice(X, nBase, 0, sB[0], w, lane);

  int cur = 0;
#pragma unroll
  for (int k0 = 0; k0 < CDIM; k0 += BK) {
    __syncthreads();
    if (k0 + BK < CDIM) {
      stage_slice(X, mBase, k0 + BK, sA[cur ^ 1], w, lane);
      stage_slice(X, nBase, k0 + BK, sB[cur ^ 1], w, lane);
    }
    half8 a[4], bfr[4];
#pragma unroll
    for (int i = 0; i < 4; ++i)
      a[i] = *(const half8*)(sA[cur] + (aRow0 + 16 * i) * BK + cswz);
#pragma unroll
    for (int i = 0; i < 4; ++i)
      bfr[i] = *(const half8*)(sB[cur] + (bRow0 + 16 * i) * BK + cswz);
#pragma unroll
    for (int mi = 0; mi < 4; ++mi)
#pragma unroll
      for (int ni = 0; ni < 4; ++ni)
        acc[mi][ni] = __builtin_amdgcn_mfma_f32_16x16x32_f16(a[mi], bfr[ni], acc[mi][ni], 0, 0, 0);
    cur ^= 1;
  }

  // epilogue: e = exp(alpha*mask*aff); store Q=e^2; column sums -> R[t]
  const int quad = lane >> 4;
  float* Qb = Q + (size_t)b * HW * HW;
  float csum[4] = {0.f, 0.f, 0.f, 0.f};
#pragma unroll
  for (int mi = 0; mi < 4; ++mi) {
#pragma unroll
    for (int r = 0; r < 4; ++r) {
      const int s = mBase + wr * 64 + mi * 16 + quad * 4 + r;
      float* orow = Qb + (size_t)s * HW;
#pragma unroll
      for (int ni = 0; ni < 4; ++ni) {
        const int t = nBase + wc * 64 + ni * 16 + (lane & 15);
        float e = __expf(alpha * mask_val(gtab, s, t) * acc[mi][ni][r]);
        csum[ni] += e;
        orow[t] = e * e;
      }
    }
  }
#pragma unroll
  for (int off = 16; off < 64; off <<= 1)
#pragma unroll
    for (int ni = 0; ni < 4; ++ni) csum[ni] += __shfl_xor(csum[ni], off);
  if (quad == 0) {
#pragma unroll
    for (int ni = 0; ni < 4; ++ni)
      atomicAdd(&R[b * HW + nBase + wc * 64 + ni * 16 + (lane & 15)], csum[ni]);
  }
}

// ------ kernel 3: stream Q -> T[t] partials + per-chunk top3 of g = Q*invR[s] ------
// grid (4 s-chunks of 1024, 64 t-stripes of 64, b)
__global__ void __launch_bounds__(256) colstats_k(const float* __restrict__ Q,
                                                  const float* __restrict__ R,
                                                  float* __restrict__ T,
                                                  float* __restrict__ part) {
  const int b = blockIdx.z;
  const float* Qb = Q + (size_t)b * HW * HW;
  const float* Rb = R + b * HW;
  const int s0 = blockIdx.x * 1024;
  const int t0 = blockIdx.y * 64;
  const int tg = threadIdx.x & 15;
  const int sr = threadIdx.x >> 4;
  float ts[4] = {0.f, 0.f, 0.f, 0.f};
  float q0[4] = {0.f, 0.f, 0.f, 0.f}, q1[4] = {0.f, 0.f, 0.f, 0.f}, q2[4] = {0.f, 0.f, 0.f, 0.f};
#pragma unroll 4
  for (int k = 0; k < 64; ++k) {
    const int s = s0 + k * 16 + sr;
    const float inv = 1.0f / Rb[s];
    f32x4 ev = *(const f32x4*)(Qb + (size_t)s * HW + t0 + tg * 4);
#pragma unroll
    for (int j = 0; j < 4; ++j) {
      float gval = ev[j] * inv;
      ts[j] += gval;
      top3_ins(gval, q0[j], q1[j], q2[j]);
    }
  }
  __shared__ float Tp[16][68], P0a[16][68], P1a[16][68], P2a[16][68];
#pragma unroll
  for (int j = 0; j < 4; ++j) {
    Tp[sr][tg * 4 + j] = ts[j];
    P0a[sr][tg * 4 + j] = q0[j];
    P1a[sr][tg * 4 + j] = q1[j];
    P2a[sr][tg * 4 + j] = q2[j];
  }
  __syncthreads();
  if (threadIdx.x < 64) {
    float tsum = 0.f, a0 = 0.f, a1 = 0.f, a2 = 0.f;
#pragma unroll
    for (int s2 = 0; s2 < 16; ++s2) {
      tsum += Tp[s2][threadIdx.x];
      top3_ins(P0a[s2][threadIdx.x], a0, a1, a2);
      top3_ins(P1a[s2][threadIdx.x], a0, a1, a2);
      top3_ins(P2a[s2][threadIdx.x], a0, a1, a2);
    }
    const int t = t0 + threadIdx.x;
    atomicAdd(&T[b * HW + t], tsum);
    float* pp = part + ((size_t)(b * 4 + blockIdx.x) * HW + t) * 3;
    pp[0] = a0;
    pp[1] = a1;
    pp[2] = a2;
  }
}

// -------- kernel 4: merge 4 top3 partials -> val; W[t] = 1/(T + 1e-8*R) --------
__global__ void __launch_bounds__(256) merge_k(const float* __restrict__ R,
                                               const float* __restrict__ T,
                                               const float* __restrict__ part,
                                               float* __restrict__ W,
                                               float* __restrict__ val_out) {
  const int idx = blockIdx.x * 256 + threadIdx.x;
  const int b = idx >> 12;
  const int t = idx & (HW - 1);
  float a0 = 0.f, a1 = 0.f, a2 = 0.f;
#pragma unroll
  for (int c = 0; c < 4; ++c) {
    const float* pp = part + ((size_t)(b * 4 + c) * HW + t) * 3;
    top3_ins(pp[0], a0, a1, a2);
    top3_ins(pp[1], a0, a1, a2);
    top3_ins(pp[2], a0, a1, a2);
  }
  const float r = R[idx];
  const float invr = 1.0f / r;
  val_out[(b * 3 + 0) * HW + t] = a0 * invr;  // col-sum C_t == R_t by symmetry
  val_out[(b * 3 + 1) * HW + t] = a1 * invr;
  val_out[(b * 3 + 2) * HW + t] = a2 * invr;
  W[idx] = 1.0f / (T[idx] + 1e-8f * r);
}

// -------- kernel 5: in-place x_soft = Q * invR[s] * W[t] over the Q region --------
__global__ void __launch_bounds__(256) writeout_k(const float* __restrict__ R,
                                                  const float* __restrict__ W,
                                                  float* __restrict__ X) {
  const int b = blockIdx.y;
  float* Xb = X + (size_t)b * HW * HW;
  const float* Wb = W + b * HW;
  const float* Rb = R + b * HW;
  const int s0 = blockIdx.x * 16;
#pragma unroll 2
  for (int row = 0; row < 16; ++row) {
    const int s = s0 + row;
    const float inv = 1.0f / Rb[s];
    float* rowp = Xb + (size_t)s * HW;
#pragma unroll
    for (int it = 0; it < 4; ++it) {
      const int t = it * 1024 + threadIdx.x * 4;
      f32x4 ev = *(const f32x4*)(rowp + t);
      f32x4 wv = *(const f32x4*)(Wb + t);
      f32x4 o;
#pragma unroll
      for (int j = 0; j < 4; ++j) o[j] = ev[j] * inv * wv[j];
      *(f32x4*)(rowp + t) = o;
    }
  }
}

extern "C" void kernel_launch(void* const* d_in, const int* in_sizes, int n_in,
                              void* d_out, int out_size, void* d_ws, size_t ws_size,
                              hipStream_t stream) {
  const float* x = (const float*)d_in[0];
  const float* alphap = (const float*)d_in[1];
  float* out = (float*)d_out;
  float* out_val = out;                 // (b,3,h,w) = 24576 floats
  float* out_x = out + 2 * 3 * HW;      // (b,hw,h,w) = Q region, transformed in place
  char* ws = (char*)d_ws;

  _Float16* Xf = (_Float16*)ws;                      // 4 MB
  float* R = (float*)(ws + (size_t)4194304);         // 32 KB
  float* T = R + 2 * HW;                             // 32 KB
  float* W = T + 2 * HW;                             // 32 KB
  float* part = W + 2 * HW;                          // 2*4*4096*3*4 = 393 KB

  hipMemsetAsync(R, 0, (size_t)2 * HW * 2 * sizeof(float), stream);  // zero R and T

  normalize_k<<<dim3(256), dim3(256), 0, stream>>>(x, Xf);
  gemmE_k<<<dim3(32, 32, 2), dim3(256), 0, stream>>>(Xf, alphap, R, out_x);
  colstats_k<<<dim3(4, 64, 2), dim3(256), 0, stream>>>(out_x, R, T, part);
  merge_k<<<dim3(32), dim3(256), 0, stream>>>(R, T, part, W, out_val);
  writeout_k<<<dim3(256, 2), dim3(256), 0, stream>>>(R, W, out_x);
}